// Round 13
// baseline (1343.767 us; speedup 1.0000x reference)
//
#include <hip/hip_runtime.h>
#include <hip/hip_bf16.h>

// Problem constants (fixed by setup_inputs)
#define BB_  64
#define TT_  512
#define FF_  1024
#define HH_  31
#define GG_  124   // 4*H
#define FUT_ 16
#define TTOT_ 528  // T + future
#define OUT_ROW_ ((size_t)TTOT_ * FF_)   // per-batch stride in output

// ---- workspace layout (float indices) ----
#define PRE1_OFF ((size_t)0)                              // [512][64][128]
#define H2A_OFF  (PRE1_OFF + (size_t)TT_*64*128)          // [528*64][32]
#define WT_OFF   (H2A_OFF  + (size_t)TTOT_*64*32)         // [31][1024]
#define MV_OFF   (WT_OFF   + 31*1024)                     // [124][32]

__device__ __forceinline__ float rdlane(float v, int k) {
    return __uint_as_float(__builtin_amdgcn_readlane(__float_as_uint(v), k));
}

// repeat macros
#define REP31(M) M(0) M(1) M(2) M(3) M(4) M(5) M(6) M(7) M(8) M(9) \
                 M(10) M(11) M(12) M(13) M(14) M(15) M(16) M(17) M(18) M(19) \
                 M(20) M(21) M(22) M(23) M(24) M(25) M(26) M(27) M(28) M(29) M(30)
#define REP16E(M) M(0) M(2) M(4) M(6) M(8) M(10) M(12) M(14) \
                  M(16) M(18) M(20) M(22) M(24) M(26) M(28) M(30)
#define REP15O(M) M(1) M(3) M(5) M(7) M(9) M(11) M(13) M(15) \
                  M(17) M(19) M(21) M(23) M(25) M(27) M(29)

// ---------------- K_FRONT: fused k1(row-per-lane, NO LDS) + k0 + k0b ----------------
// k1 role (blocks 0..255): thread = (row m, gate-half). 62 accumulators in
// registers; per K-chunk of 4, X float4 is per-lane, the 62 W float4 loads are
// WAVE-UNIFORM (g0 forced to SGPR via readfirstlane -> s_load path, scalar pipe
// parallel to VALU). No LDS, no barriers, no tile staging -- the R0/R8/R12
// LDS-tiled k1 variants all stalled at 300-350us vs a ~55us issue floor
// (1 wave/SIMD + 64 barriers + LDS round trips). VALU floor here: 62*1024 FMA
// /thread = 127k cy ~ 53us at 1 wave/SIMD with nothing to wait on but L2.
// Accumulation chain per output is k-ascending sequential adds -- textually
// the same chain as R0's (kc asc, k asc) -> pre1 BIT-IDENTICAL.
// blocks 256..379: k0 (WT transpose). blocks 380..395: k0b (Mv).
__global__ __launch_bounds__(256) void k_front(
    const float* __restrict__ X,      // [B][T][F] fp32
    const float* __restrict__ Wih1,   // [G][F] fp32
    const float* __restrict__ bih1,
    const float* __restrict__ bhh1,
    const float* __restrict__ Wlin,   // [1024][31]
    const float* __restrict__ blin,   // [1024]
    float* __restrict__ pre1,         // [T][B][128]
    float* __restrict__ WT,           // [31][1024]
    float* __restrict__ Mv)           // [124][32]
{
    const int blk = blockIdx.x;
    const int tid = threadIdx.x;

    if (blk < 256) {
        // ---------------- k1 role ----------------
        const int lrow = tid & 127;                    // 0..127
        const int m    = blk * 128 + lrow;             // row 0..32767
        const int t    = m >> 6, b = m & 63;
        // gate base: wave-uniform (tid>>7 constant per wave); force to SGPR
        const int g0   = __builtin_amdgcn_readfirstlane((tid >> 7) * 62);
        const float* xrow  = X + (size_t)b * TT_ * FF_ + (size_t)t * FF_;
        const float* wbase = Wih1 + (size_t)g0 * FF_;

        float acc[62];
#pragma unroll
        for (int g = 0; g < 62; g++) acc[g] = 0.0f;

        float4 xv = *(const float4*)(xrow);            // prefetch chunk 0
        for (int kc = 0; kc < FF_; kc += 4) {
            const float4 xc = xv;
            const int kn = (kc + 4 < FF_) ? (kc + 4) : 0;   // guarded prefetch
            xv = *(const float4*)(xrow + kn);
#pragma unroll
            for (int g = 0; g < 62; g++) {
                float4 wv = *(const float4*)(wbase + (size_t)g * FF_ + kc);
                // k-ascending sequential adds: same chain as verified R0 k1
                acc[g] += xc.x * wv.x;
                acc[g] += xc.y * wv.y;
                acc[g] += xc.z * wv.z;
                acc[g] += xc.w * wv.w;
            }
        }
        // bias + store (per-lane 248B contiguous -> sector-complete writes)
#pragma unroll
        for (int g = 0; g < 62; g++) {
            pre1[(size_t)m * 128 + g0 + g] = acc[g] + (bih1[g0 + g] + bhh1[g0 + g]);
        }
        // zero pad columns 124..127 (k2's dummy lanes read them; keep finite)
        if (tid < 128) {
            *(float4*)(pre1 + (size_t)m * 128 + 124) = make_float4(0.f, 0.f, 0.f, 0.f);
        }
    } else if (blk < 380) {
        // ---------------- k0 role: transpose W_lin ----------------
        int i = (blk - 256) * 256 + tid;   // 124*256 = 31744 = 1024*31
        int j = i / 31;
        int k = i - j * 31;
        WT[k * 1024 + j] = Wlin[i];
    } else {
        // ---------------- k0b role: Mv ----------------
        int idx = (blk - 380) * 256 + tid;
        if (idx < GG_ * 32) {
            int g = idx >> 5, k = idx & 31;
            const float* wr = Wih1 + (size_t)g * FF_;
            float acc = 0.0f;
            if (k < 31) {
#pragma unroll 8
                for (int j = 0; j < FF_; j++) acc += wr[j] * Wlin[j * 31 + k];
            } else {
#pragma unroll 8
                for (int j = 0; j < FF_; j++) acc += wr[j] * blin[j];
            }
            Mv[idx] = acc;
        }
    }
}

// ---------------- K2: sequential recurrence (R6 version, verified 360us) ----------------
// Merged-phase (L2(t)+L1(t+1), one barrier/step), split state ownership
// (lanes 0..30 own layer-2 state, lanes 32..62 own layer-1 state), split
// accumulator chains (dep depth 62->16), 2-step pre1 prefetch.
// R7 (4-batch TLP), R11/R12 (intra-kernel overlap with producers/consumers)
// all regressed: ANY co-residency degrades this latency-critical loop.
// Runs solo. Bit-identical output.
__global__ __attribute__((amdgpu_flat_work_group_size(128, 128), amdgpu_waves_per_eu(1)))
void k2_recur(
    const float* __restrict__ pre1,   // [T][B][128]  (bias already folded in)
    const float* __restrict__ Whh1,   // [G][H]
    const float* __restrict__ Wih2,   // [G][H]
    const float* __restrict__ Whh2,   // [G][H]
    const float* __restrict__ bih1, const float* __restrict__ bhh1,
    const float* __restrict__ bih2, const float* __restrict__ bhh2,
    const float* __restrict__ Mv,     // [124][32]  (M | v)
    float* __restrict__ h2a)          // [528*64][32]
{
    __shared__ float gA[2][128];      // layer-1 activated gates (double-buffered)
    __shared__ float g2[2][128];      // layer-2 activated gates (double-buffered)
    const int L  = threadIdx.x;       // 0..127
    const int bb = blockIdx.x;
    const int j  = L & 63;            // in-wave lane
    const int gc = (L < GG_) ? L : (GG_ - 1);   // clamped gate id for safe loads
    const bool isg = (gc >= 62 && gc < 93);     // tanh gate?
    const bool selhi = (j >= 32);               // h1-owner half of the wave
    const int sidx = selhi ? (j - 32) : j;      // state index this lane owns

    // recurrent weights as NAMED scalars: row gc of each [124][31] matrix
#define WLOAD(k) float w1_##k  = Whh1[gc * 31 + k]; \
                 float wi2_##k = Wih2[gc * 31 + k]; \
                 float wh2_##k = Whh2[gc * 31 + k];
    REP31(WLOAD)
#undef WLOAD
#define WPIN(k) asm("" : "+v"(w1_##k), "+v"(wi2_##k), "+v"(wh2_##k));
    REP31(WPIN)
#undef WPIN

    const float b2c = bih2[gc] + bhh2[gc];

    // unified state: lanes 0..30 hold (cv2,hv2)[j]; lanes 32..62 hold (cv1,hv1)[j-32]
    float hv = 0.0f, cv = 0.0f;

    // ---- prologue: layer-1 gates for t=0 (h1(-1)=0 -> dot contributes zeros) ----
    float cur0 = pre1[(size_t)bb * 128 + L];
    float pnxt = pre1[((size_t)1 * 64 + bb) * 128 + L];   // p(1)
    float pnx2 = pre1[((size_t)2 * 64 + bb) * 128 + L];   // p(2)
    {
        float pa0 = cur0, pa1 = 0.0f;
#define DPE(k) { float hk = rdlane(hv, 32 + k); pa0 += w1_##k * hk; }
#define DPO(k) { float hk = rdlane(hv, 32 + k); pa1 += w1_##k * hk; }
        REP16E(DPE)
        REP15O(DPO)
#undef DPE
#undef DPO
        float a = pa0 + pa1;
        float z = isg ? (2.0f * a) : a;
        float s = 1.0f / (1.0f + __expf(-z));
        gA[1][L] = isg ? (2.0f * s - 1.0f) : s;
    }
    __syncthreads();
    {
        // h1-owners (lanes 32..62) take h1(0); h2-owners stay at 0
        const float* gsrc = &gA[1][0];
        float ig = gsrc[sidx];
        float fg = gsrc[sidx + 31];
        float gg = gsrc[sidx + 62];
        float og = gsrc[sidx + 93];
        float cvn = fg * cv + ig * gg;
        float e = __expf(-2.0f * cvn);
        float hvn = og * (2.0f / (1.0f + e) - 1.0f);
        cv = selhi ? cvn : 0.0f;
        hv = selhi ? hvn : 0.0f;
    }

    // ---- main merged loop: iteration t computes L2(t) + L1(t+1), t = 0..510 ----
    for (int t = 0; t < TT_ - 1; t++) {
        const int pb = t & 1;
        const float cur = pnxt;
        pnxt = pnx2;
        if (t + 3 < TT_) pnx2 = pre1[((size_t)(t + 3) * 64 + bb) * 128 + L];

        // split-chain dots: h1k = rdlane(hv,32+k), h2k = rdlane(hv,k)
        float bi0 = b2c, bi1 = 0.0f, bh0 = 0.0f, bh1 = 0.0f;
        float pa0 = cur, pa1 = 0.0f;
#define DME(k) { float h1k = rdlane(hv, 32 + k); float h2k = rdlane(hv, k); \
                 bi0 += wi2_##k * h1k; bh0 += wh2_##k * h2k; pa0 += w1_##k * h1k; }
#define DMO(k) { float h1k = rdlane(hv, 32 + k); float h2k = rdlane(hv, k); \
                 bi1 += wi2_##k * h1k; bh1 += wh2_##k * h2k; pa1 += w1_##k * h1k; }
        REP16E(DME)
        REP15O(DMO)
#undef DME
#undef DMO
        float b = (bi0 + bi1) + (bh0 + bh1);
        float a = pa0 + pa1;
        {
            float z = isg ? (2.0f * b) : b;
            float s = 1.0f / (1.0f + __expf(-z));
            g2[pb][L] = isg ? (2.0f * s - 1.0f) : s;
        }
        {
            float z = isg ? (2.0f * a) : a;
            float s = 1.0f / (1.0f + __expf(-z));
            gA[pb][L] = isg ? (2.0f * s - 1.0f) : s;
        }
        __syncthreads();
        {
            // unified branchless state update: h2-owners read g2 (L2 gates of t),
            // h1-owners read gA (L1 gates of t+1).
            const float* gsrc = selhi ? &gA[pb][0] : &g2[pb][0];
            float ig = gsrc[sidx];
            float fg = gsrc[sidx + 31];
            float gg = gsrc[sidx + 62];
            float og = gsrc[sidx + 93];
            cv = fg * cv + ig * gg;
            float e = __expf(-2.0f * cv);
            hv = og * (2.0f / (1.0f + e) - 1.0f);
        }
        if (L < HH_) h2a[((size_t)t * 64 + bb) * 32 + L] = hv;   // h2(t)
    }

    // ---- tail: L2(511) only ----
    {
        float bi0 = b2c, bi1 = 0.0f, bh0 = 0.0f, bh1 = 0.0f;
#define DTE(k) { float h1k = rdlane(hv, 32 + k); float h2k = rdlane(hv, k); \
                 bi0 += wi2_##k * h1k; bh0 += wh2_##k * h2k; }
#define DTO(k) { float h1k = rdlane(hv, 32 + k); float h2k = rdlane(hv, k); \
                 bi1 += wi2_##k * h1k; bh1 += wh2_##k * h2k; }
        REP16E(DTE)
        REP15O(DTO)
#undef DTE
#undef DTO
        float b = (bi0 + bi1) + (bh0 + bh1);
        float z = isg ? (2.0f * b) : b;
        float s = 1.0f / (1.0f + __expf(-z));
        g2[1][L] = isg ? (2.0f * s - 1.0f) : s;
    }
    __syncthreads();
    {
        const float* gsrc = &g2[1][0];
        float ig = gsrc[sidx];
        float fg = gsrc[sidx + 31];
        float gg = gsrc[sidx + 62];
        float og = gsrc[sidx + 93];
        float cvn = fg * cv + ig * gg;
        float e = __expf(-2.0f * cvn);
        float hvn = og * (2.0f / (1.0f + e) - 1.0f);
        cv = selhi ? cv : cvn;          // only h2-owners update
        hv = selhi ? hv : hvn;
    }
    if (L < HH_) h2a[((size_t)(TT_ - 1) * 64 + bb) * 32 + L] = hv;   // h2(511)

    // ---- autoregressive future: pregate = M*h2 + v + b1 (1024-dot eliminated) ----
#define MLOAD(k) float m_##k = Mv[gc * 32 + k];
    REP31(MLOAD)
#undef MLOAD
    float m_31 = Mv[gc * 32 + 31];
#define MPIN(k) asm("" : "+v"(m_##k));
    REP31(MPIN)
#undef MPIN
    asm("" : "+v"(m_31));
    const float b1c = bih1[gc] + bhh1[gc];

    for (int sft = 0; sft < FUT_; sft++) {
        float pa0 = b1c + m_31, pa1 = 0.0f;
#define DFE(k) { float h2k = rdlane(hv, k); pa0 += m_##k * h2k; }
#define DFO(k) { float h2k = rdlane(hv, k); pa1 += m_##k * h2k; }
        REP16E(DFE)
        REP15O(DFO)
#undef DFE
#undef DFO
#define DGE(k) { float h1k = rdlane(hv, 32 + k); pa0 += w1_##k * h1k; }
#define DGO(k) { float h1k = rdlane(hv, 32 + k); pa1 += w1_##k * h1k; }
        REP16E(DGE)
        REP15O(DGO)
#undef DGE
#undef DGO
        {
            float a = pa0 + pa1;
            float z = isg ? (2.0f * a) : a;
            float s = 1.0f / (1.0f + __expf(-z));
            gA[0][L] = isg ? (2.0f * s - 1.0f) : s;
        }
        __syncthreads();
        {
            const float* gsrc = &gA[0][0];
            float ig = gsrc[sidx];
            float fg = gsrc[sidx + 31];
            float gg = gsrc[sidx + 62];
            float og = gsrc[sidx + 93];
            float cvn = fg * cv + ig * gg;
            float e = __expf(-2.0f * cvn);
            float hvn = og * (2.0f / (1.0f + e) - 1.0f);
            cv = selhi ? cvn : cv;      // only h1-owners update
            hv = selhi ? hvn : hv;
        }
        float bi0 = b2c, bi1 = 0.0f, bh0 = 0.0f, bh1 = 0.0f;
#define DHE(k) { float h1k = rdlane(hv, 32 + k); float h2k = rdlane(hv, k); \
                 bi0 += wi2_##k * h1k; bh0 += wh2_##k * h2k; }
#define DHO(k) { float h1k = rdlane(hv, 32 + k); float h2k = rdlane(hv, k); \
                 bi1 += wi2_##k * h1k; bh1 += wh2_##k * h2k; }
        REP16E(DHE)
        REP15O(DHO)
#undef DHE
#undef DHO
        {
            float b = (bi0 + bi1) + (bh0 + bh1);
            float z = isg ? (2.0f * b) : b;
            float s = 1.0f / (1.0f + __expf(-z));
            g2[0][L] = isg ? (2.0f * s - 1.0f) : s;
        }
        __syncthreads();
        {
            const float* gsrc = &g2[0][0];
            float ig = gsrc[sidx];
            float fg = gsrc[sidx + 31];
            float gg = gsrc[sidx + 62];
            float og = gsrc[sidx + 93];
            float cvn = fg * cv + ig * gg;
            float e = __expf(-2.0f * cvn);
            float hvn = og * (2.0f / (1.0f + e) - 1.0f);
            cv = selhi ? cv : cvn;      // only h2-owners update
            hv = selhi ? hv : hvn;
        }
        if (L < HH_) h2a[((size_t)(TT_ + sft) * 64 + bb) * 32 + L] = hv;
    }
}

// ---------------- K3 v2: output linear, 32 rows/block (R9 verified) ----------------
__global__ __launch_bounds__(256) void k3_outlin(
    const float* __restrict__ h2a,   // [528*64][32]
    const float* __restrict__ WT,    // [31][1024]
    const float* __restrict__ blin,  // [1024]
    float* __restrict__ out)         // [B][528][1024] fp32
{
    __shared__ __align__(16) float hl[32][32];
    const int tid = threadIdx.x;
    const int m0  = blockIdx.x * 32;
#pragma unroll
    for (int p = 0; p < 4; p++) {
        int i = tid + p * 256;
        int r = i >> 5, k = i & 31;
        hl[r][k] = h2a[(size_t)(m0 + r) * 32 + k];
    }
    __syncthreads();
    const int c0 = tid * 4;
    float4 bl = *(const float4*)(blin + c0);
    float4 acc[32];
#pragma unroll
    for (int r = 0; r < 32; r++) acc[r] = bl;
    for (int k = 0; k < 31; k++) {
        float4 wv = *(const float4*)(WT + k * 1024 + c0);
#pragma unroll
        for (int r = 0; r < 32; r++) {
            float h = hl[r][k];
            acc[r].x += h * wv.x; acc[r].y += h * wv.y;
            acc[r].z += h * wv.z; acc[r].w += h * wv.w;
        }
    }
    const int t  = m0 >> 6;
    const int b0 = m0 & 63;
#pragma unroll
    for (int r = 0; r < 32; r++) {
        int b = b0 + r;
        *(float4*)(out + (size_t)b * OUT_ROW_ + (size_t)t * FF_ + c0) = acc[r];
    }
}

extern "C" void kernel_launch(void* const* d_in, const int* in_sizes, int n_in,
                              void* d_out, int out_size, void* d_ws, size_t ws_size,
                              hipStream_t stream) {
    (void)in_sizes; (void)n_in; (void)out_size; (void)ws_size;
    const float* X    = (const float*)d_in[0];
    const float* Wih1 = (const float*)d_in[1];
    const float* Whh1 = (const float*)d_in[2];
    const float* bih1 = (const float*)d_in[3];
    const float* bhh1 = (const float*)d_in[4];
    const float* Wih2 = (const float*)d_in[5];
    const float* Whh2 = (const float*)d_in[6];
    const float* bih2 = (const float*)d_in[7];
    const float* bhh2 = (const float*)d_in[8];
    const float* Wlin = (const float*)d_in[9];
    const float* blin = (const float*)d_in[10];
    // d_in[11] = future = 16 (constant for this problem)

    float* ws   = (float*)d_ws;
    float* pre1 = ws + PRE1_OFF;
    float* h2a  = ws + H2A_OFF;
    float* WT   = ws + WT_OFF;
    float* Mv   = ws + MV_OFF;
    float* out  = (float*)d_out;

    hipLaunchKernelGGL(k_front,   dim3(396),     dim3(256), 0, stream,
                       X, Wih1, bih1, bhh1, Wlin, blin, pre1, WT, Mv);
    hipLaunchKernelGGL(k2_recur,  dim3(BB_),     dim3(128), 0, stream, pre1, Whh1, Wih2, Whh2,
                       bih1, bhh1, bih2, bhh2, Mv, h2a);
    hipLaunchKernelGGL(k3_outlin, dim3(TTOT_*2), dim3(256), 0, stream, h2a, WT, blin, out);
}

// Round 14
// 1014.522 us; speedup vs baseline: 1.3245x; 1.3245x over previous
//
#include <hip/hip_runtime.h>
#include <hip/hip_bf16.h>

// Problem constants (fixed by setup_inputs)
#define BB_  64
#define TT_  512
#define FF_  1024
#define HH_  31
#define GG_  124   // 4*H
#define FUT_ 16
#define TTOT_ 528  // T + future
#define OUT_ROW_ ((size_t)TTOT_ * FF_)   // per-batch stride in output

// ---- workspace layout (float indices) ----
#define PRE1_OFF ((size_t)0)                              // [512][64][128]
#define H2A_OFF  (PRE1_OFF + (size_t)TT_*64*128)          // [528*64][32]
#define WT_OFF   (H2A_OFF  + (size_t)TTOT_*64*32)         // [31][1024]
#define MV_OFF   (WT_OFF   + 31*1024)                     // [124][32]

__device__ __forceinline__ float rdlane(float v, int k) {
    return __uint_as_float(__builtin_amdgcn_readlane(__float_as_uint(v), k));
}

// repeat macros
#define REP31(M) M(0) M(1) M(2) M(3) M(4) M(5) M(6) M(7) M(8) M(9) \
                 M(10) M(11) M(12) M(13) M(14) M(15) M(16) M(17) M(18) M(19) \
                 M(20) M(21) M(22) M(23) M(24) M(25) M(26) M(27) M(28) M(29) M(30)
#define REP16E(M) M(0) M(2) M(4) M(6) M(8) M(10) M(12) M(14) \
                  M(16) M(18) M(20) M(22) M(24) M(26) M(28) M(30)
#define REP15O(M) M(1) M(3) M(5) M(7) M(9) M(11) M(13) M(15) \
                  M(17) M(19) M(21) M(23) M(25) M(27) M(29)

// ---------------- K_FRONT: fused k1(no-LDS, NAMED-SCALAR acc) + k0 + k0b ----------------
// k1 role (blocks 0..511, one timestep each): 256 threads = 64 rows x 4
// gate-quarters. Wave q (q=tid>>6, wave-uniform) owns gates q*31..q*31+30
// (4x31 = 124 exactly). 31 accumulators as NAMED SCALARS (REP31) -- R13's
// acc[62] array was left rolled by the compiler and spilled to scratch
// (VGPR_Count=40, WRITE_SIZE 54-81MB of scratch traffic, 782us). Named
// loop-carried scalars cannot be rematerialized or runtime-indexed -> they
// MUST get VGPRs (~31+temps, well under budget).
// W loads are wave-uniform-address (g0 via readfirstlane -> SGPR path);
// the 4 quarter-waves share the block's 64 X rows -> L1 hits.
// Accumulation chain per output is k-ascending sequential adds == R0's chain
// -> pre1 BIT-IDENTICAL (absmax must stay 0.001953125).
// blocks 512..635: k0 (WT transpose). blocks 636..651: k0b (Mv).
__global__ __launch_bounds__(256) void k_front(
    const float* __restrict__ X,      // [B][T][F] fp32
    const float* __restrict__ Wih1,   // [G][F] fp32
    const float* __restrict__ bih1,
    const float* __restrict__ bhh1,
    const float* __restrict__ Wlin,   // [1024][31]
    const float* __restrict__ blin,   // [1024]
    float* __restrict__ pre1,         // [T][B][128]
    float* __restrict__ WT,           // [31][1024]
    float* __restrict__ Mv)           // [124][32]
{
    const int blk = blockIdx.x;
    const int tid = threadIdx.x;

    if (blk < 512) {
        // ---------------- k1 role: t = blk, row b = tid&63, quarter q = tid>>6 ----
        const int b  = tid & 63;
        const int t  = blk;
        const int g0 = __builtin_amdgcn_readfirstlane((tid >> 6) * 31);  // 0/31/62/93
        const float* xrow  = X + (size_t)b * TT_ * FF_ + (size_t)t * FF_;
        const float* wbase = Wih1 + (size_t)g0 * FF_;

#define ADECL(k) float a_##k = 0.0f;
        REP31(ADECL)
#undef ADECL

        float4 xv = *(const float4*)(xrow);            // prefetch chunk 0
        for (int kc = 0; kc < FF_; kc += 4) {
            const float4 xc = xv;
            const int kn = (kc + 4 < FF_) ? (kc + 4) : 0;   // guarded prefetch
            xv = *(const float4*)(xrow + kn);
#define WFMA(k) { float4 wv = *(const float4*)(wbase + (size_t)k * FF_ + kc); \
                  a_##k += xc.x * wv.x; \
                  a_##k += xc.y * wv.y; \
                  a_##k += xc.z * wv.z; \
                  a_##k += xc.w * wv.w; }
            REP31(WFMA)
#undef WFMA
        }
        // bias + store (k-ascending chain finished; same expression as R0: acc + (b1+b2))
        const int m = t * 64 + b;
        float* prow = pre1 + (size_t)m * 128 + g0;
#define STG(k) prow[k] = a_##k + (bih1[g0 + k] + bhh1[g0 + k]);
        REP31(STG)
#undef STG
        // zero pad columns 124..127 (k2's dummy lanes read them; keep finite)
        if ((tid >> 6) == 3) {
            *(float4*)(pre1 + (size_t)m * 128 + 124) = make_float4(0.f, 0.f, 0.f, 0.f);
        }
    } else if (blk < 636) {
        // ---------------- k0 role: transpose W_lin ----------------
        int i = (blk - 512) * 256 + tid;   // 124*256 = 31744 = 1024*31
        int j = i / 31;
        int k = i - j * 31;
        WT[k * 1024 + j] = Wlin[i];
    } else {
        // ---------------- k0b role: Mv ----------------
        int idx = (blk - 636) * 256 + tid;
        if (idx < GG_ * 32) {
            int g = idx >> 5, k = idx & 31;
            const float* wr = Wih1 + (size_t)g * FF_;
            float acc = 0.0f;
            if (k < 31) {
#pragma unroll 8
                for (int j = 0; j < FF_; j++) acc += wr[j] * Wlin[j * 31 + k];
            } else {
#pragma unroll 8
                for (int j = 0; j < FF_; j++) acc += wr[j] * blin[j];
            }
            Mv[idx] = acc;
        }
    }
}

// ---------------- K2: sequential recurrence (R6 version, verified 360us) ----------------
// Merged-phase (L2(t)+L1(t+1), one barrier/step), split state ownership
// (lanes 0..30 own layer-2 state, lanes 32..62 own layer-1 state), split
// accumulator chains (dep depth 62->16), 2-step pre1 prefetch.
// R7 (4-batch TLP), R11/R12 (intra-kernel overlap) all regressed: ANY
// co-residency degrades this latency-critical loop. Runs solo. Bit-identical.
__global__ __attribute__((amdgpu_flat_work_group_size(128, 128), amdgpu_waves_per_eu(1)))
void k2_recur(
    const float* __restrict__ pre1,   // [T][B][128]  (bias already folded in)
    const float* __restrict__ Whh1,   // [G][H]
    const float* __restrict__ Wih2,   // [G][H]
    const float* __restrict__ Whh2,   // [G][H]
    const float* __restrict__ bih1, const float* __restrict__ bhh1,
    const float* __restrict__ bih2, const float* __restrict__ bhh2,
    const float* __restrict__ Mv,     // [124][32]  (M | v)
    float* __restrict__ h2a)          // [528*64][32]
{
    __shared__ float gA[2][128];      // layer-1 activated gates (double-buffered)
    __shared__ float g2[2][128];      // layer-2 activated gates (double-buffered)
    const int L  = threadIdx.x;       // 0..127
    const int bb = blockIdx.x;
    const int j  = L & 63;            // in-wave lane
    const int gc = (L < GG_) ? L : (GG_ - 1);   // clamped gate id for safe loads
    const bool isg = (gc >= 62 && gc < 93);     // tanh gate?
    const bool selhi = (j >= 32);               // h1-owner half of the wave
    const int sidx = selhi ? (j - 32) : j;      // state index this lane owns

    // recurrent weights as NAMED scalars: row gc of each [124][31] matrix
#define WLOAD(k) float w1_##k  = Whh1[gc * 31 + k]; \
                 float wi2_##k = Wih2[gc * 31 + k]; \
                 float wh2_##k = Whh2[gc * 31 + k];
    REP31(WLOAD)
#undef WLOAD
#define WPIN(k) asm("" : "+v"(w1_##k), "+v"(wi2_##k), "+v"(wh2_##k));
    REP31(WPIN)
#undef WPIN

    const float b2c = bih2[gc] + bhh2[gc];

    // unified state: lanes 0..30 hold (cv2,hv2)[j]; lanes 32..62 hold (cv1,hv1)[j-32]
    float hv = 0.0f, cv = 0.0f;

    // ---- prologue: layer-1 gates for t=0 (h1(-1)=0 -> dot contributes zeros) ----
    float cur0 = pre1[(size_t)bb * 128 + L];
    float pnxt = pre1[((size_t)1 * 64 + bb) * 128 + L];   // p(1)
    float pnx2 = pre1[((size_t)2 * 64 + bb) * 128 + L];   // p(2)
    {
        float pa0 = cur0, pa1 = 0.0f;
#define DPE(k) { float hk = rdlane(hv, 32 + k); pa0 += w1_##k * hk; }
#define DPO(k) { float hk = rdlane(hv, 32 + k); pa1 += w1_##k * hk; }
        REP16E(DPE)
        REP15O(DPO)
#undef DPE
#undef DPO
        float a = pa0 + pa1;
        float z = isg ? (2.0f * a) : a;
        float s = 1.0f / (1.0f + __expf(-z));
        gA[1][L] = isg ? (2.0f * s - 1.0f) : s;
    }
    __syncthreads();
    {
        // h1-owners (lanes 32..62) take h1(0); h2-owners stay at 0
        const float* gsrc = &gA[1][0];
        float ig = gsrc[sidx];
        float fg = gsrc[sidx + 31];
        float gg = gsrc[sidx + 62];
        float og = gsrc[sidx + 93];
        float cvn = fg * cv + ig * gg;
        float e = __expf(-2.0f * cvn);
        float hvn = og * (2.0f / (1.0f + e) - 1.0f);
        cv = selhi ? cvn : 0.0f;
        hv = selhi ? hvn : 0.0f;
    }

    // ---- main merged loop: iteration t computes L2(t) + L1(t+1), t = 0..510 ----
    for (int t = 0; t < TT_ - 1; t++) {
        const int pb = t & 1;
        const float cur = pnxt;
        pnxt = pnx2;
        if (t + 3 < TT_) pnx2 = pre1[((size_t)(t + 3) * 64 + bb) * 128 + L];

        // split-chain dots: h1k = rdlane(hv,32+k), h2k = rdlane(hv,k)
        float bi0 = b2c, bi1 = 0.0f, bh0 = 0.0f, bh1 = 0.0f;
        float pa0 = cur, pa1 = 0.0f;
#define DME(k) { float h1k = rdlane(hv, 32 + k); float h2k = rdlane(hv, k); \
                 bi0 += wi2_##k * h1k; bh0 += wh2_##k * h2k; pa0 += w1_##k * h1k; }
#define DMO(k) { float h1k = rdlane(hv, 32 + k); float h2k = rdlane(hv, k); \
                 bi1 += wi2_##k * h1k; bh1 += wh2_##k * h2k; pa1 += w1_##k * h1k; }
        REP16E(DME)
        REP15O(DMO)
#undef DME
#undef DMO
        float b = (bi0 + bi1) + (bh0 + bh1);
        float a = pa0 + pa1;
        {
            float z = isg ? (2.0f * b) : b;
            float s = 1.0f / (1.0f + __expf(-z));
            g2[pb][L] = isg ? (2.0f * s - 1.0f) : s;
        }
        {
            float z = isg ? (2.0f * a) : a;
            float s = 1.0f / (1.0f + __expf(-z));
            gA[pb][L] = isg ? (2.0f * s - 1.0f) : s;
        }
        __syncthreads();
        {
            // unified branchless state update: h2-owners read g2 (L2 gates of t),
            // h1-owners read gA (L1 gates of t+1).
            const float* gsrc = selhi ? &gA[pb][0] : &g2[pb][0];
            float ig = gsrc[sidx];
            float fg = gsrc[sidx + 31];
            float gg = gsrc[sidx + 62];
            float og = gsrc[sidx + 93];
            cv = fg * cv + ig * gg;
            float e = __expf(-2.0f * cv);
            hv = og * (2.0f / (1.0f + e) - 1.0f);
        }
        if (L < HH_) h2a[((size_t)t * 64 + bb) * 32 + L] = hv;   // h2(t)
    }

    // ---- tail: L2(511) only ----
    {
        float bi0 = b2c, bi1 = 0.0f, bh0 = 0.0f, bh1 = 0.0f;
#define DTE(k) { float h1k = rdlane(hv, 32 + k); float h2k = rdlane(hv, k); \
                 bi0 += wi2_##k * h1k; bh0 += wh2_##k * h2k; }
#define DTO(k) { float h1k = rdlane(hv, 32 + k); float h2k = rdlane(hv, k); \
                 bi1 += wi2_##k * h1k; bh1 += wh2_##k * h2k; }
        REP16E(DTE)
        REP15O(DTO)
#undef DTE
#undef DTO
        float b = (bi0 + bi1) + (bh0 + bh1);
        float z = isg ? (2.0f * b) : b;
        float s = 1.0f / (1.0f + __expf(-z));
        g2[1][L] = isg ? (2.0f * s - 1.0f) : s;
    }
    __syncthreads();
    {
        const float* gsrc = &g2[1][0];
        float ig = gsrc[sidx];
        float fg = gsrc[sidx + 31];
        float gg = gsrc[sidx + 62];
        float og = gsrc[sidx + 93];
        float cvn = fg * cv + ig * gg;
        float e = __expf(-2.0f * cvn);
        float hvn = og * (2.0f / (1.0f + e) - 1.0f);
        cv = selhi ? cv : cvn;          // only h2-owners update
        hv = selhi ? hv : hvn;
    }
    if (L < HH_) h2a[((size_t)(TT_ - 1) * 64 + bb) * 32 + L] = hv;   // h2(511)

    // ---- autoregressive future: pregate = M*h2 + v + b1 (1024-dot eliminated) ----
#define MLOAD(k) float m_##k = Mv[gc * 32 + k];
    REP31(MLOAD)
#undef MLOAD
    float m_31 = Mv[gc * 32 + 31];
#define MPIN(k) asm("" : "+v"(m_##k));
    REP31(MPIN)
#undef MPIN
    asm("" : "+v"(m_31));
    const float b1c = bih1[gc] + bhh1[gc];

    for (int sft = 0; sft < FUT_; sft++) {
        float pa0 = b1c + m_31, pa1 = 0.0f;
#define DFE(k) { float h2k = rdlane(hv, k); pa0 += m_##k * h2k; }
#define DFO(k) { float h2k = rdlane(hv, k); pa1 += m_##k * h2k; }
        REP16E(DFE)
        REP15O(DFO)
#undef DFE
#undef DFO
#define DGE(k) { float h1k = rdlane(hv, 32 + k); pa0 += w1_##k * h1k; }
#define DGO(k) { float h1k = rdlane(hv, 32 + k); pa1 += w1_##k * h1k; }
        REP16E(DGE)
        REP15O(DGO)
#undef DGE
#undef DGO
        {
            float a = pa0 + pa1;
            float z = isg ? (2.0f * a) : a;
            float s = 1.0f / (1.0f + __expf(-z));
            gA[0][L] = isg ? (2.0f * s - 1.0f) : s;
        }
        __syncthreads();
        {
            const float* gsrc = &gA[0][0];
            float ig = gsrc[sidx];
            float fg = gsrc[sidx + 31];
            float gg = gsrc[sidx + 62];
            float og = gsrc[sidx + 93];
            float cvn = fg * cv + ig * gg;
            float e = __expf(-2.0f * cvn);
            float hvn = og * (2.0f / (1.0f + e) - 1.0f);
            cv = selhi ? cvn : cv;      // only h1-owners update
            hv = selhi ? hvn : hv;
        }
        float bi0 = b2c, bi1 = 0.0f, bh0 = 0.0f, bh1 = 0.0f;
#define DHE(k) { float h1k = rdlane(hv, 32 + k); float h2k = rdlane(hv, k); \
                 bi0 += wi2_##k * h1k; bh0 += wh2_##k * h2k; }
#define DHO(k) { float h1k = rdlane(hv, 32 + k); float h2k = rdlane(hv, k); \
                 bi1 += wi2_##k * h1k; bh1 += wh2_##k * h2k; }
        REP16E(DHE)
        REP15O(DHO)
#undef DHE
#undef DHO
        {
            float b = (bi0 + bi1) + (bh0 + bh1);
            float z = isg ? (2.0f * b) : b;
            float s = 1.0f / (1.0f + __expf(-z));
            g2[0][L] = isg ? (2.0f * s - 1.0f) : s;
        }
        __syncthreads();
        {
            const float* gsrc = &g2[0][0];
            float ig = gsrc[sidx];
            float fg = gsrc[sidx + 31];
            float gg = gsrc[sidx + 62];
            float og = gsrc[sidx + 93];
            float cvn = fg * cv + ig * gg;
            float e = __expf(-2.0f * cvn);
            float hvn = og * (2.0f / (1.0f + e) - 1.0f);
            cv = selhi ? cv : cvn;      // only h2-owners update
            hv = selhi ? hv : hvn;
        }
        if (L < HH_) h2a[((size_t)(TT_ + sft) * 64 + bb) * 32 + L] = hv;
    }
}

// ---------------- K3 v2: output linear, 32 rows/block (R9 verified) ----------------
__global__ __launch_bounds__(256) void k3_outlin(
    const float* __restrict__ h2a,   // [528*64][32]
    const float* __restrict__ WT,    // [31][1024]
    const float* __restrict__ blin,  // [1024]
    float* __restrict__ out)         // [B][528][1024] fp32
{
    __shared__ __align__(16) float hl[32][32];
    const int tid = threadIdx.x;
    const int m0  = blockIdx.x * 32;
#pragma unroll
    for (int p = 0; p < 4; p++) {
        int i = tid + p * 256;
        int r = i >> 5, k = i & 31;
        hl[r][k] = h2a[(size_t)(m0 + r) * 32 + k];
    }
    __syncthreads();
    const int c0 = tid * 4;
    float4 bl = *(const float4*)(blin + c0);
    float4 acc[32];
#pragma unroll
    for (int r = 0; r < 32; r++) acc[r] = bl;
    for (int k = 0; k < 31; k++) {
        float4 wv = *(const float4*)(WT + k * 1024 + c0);
#pragma unroll
        for (int r = 0; r < 32; r++) {
            float h = hl[r][k];
            acc[r].x += h * wv.x; acc[r].y += h * wv.y;
            acc[r].z += h * wv.z; acc[r].w += h * wv.w;
        }
    }
    const int t  = m0 >> 6;
    const int b0 = m0 & 63;
#pragma unroll
    for (int r = 0; r < 32; r++) {
        int b = b0 + r;
        *(float4*)(out + (size_t)b * OUT_ROW_ + (size_t)t * FF_ + c0) = acc[r];
    }
}

extern "C" void kernel_launch(void* const* d_in, const int* in_sizes, int n_in,
                              void* d_out, int out_size, void* d_ws, size_t ws_size,
                              hipStream_t stream) {
    (void)in_sizes; (void)n_in; (void)out_size; (void)ws_size;
    const float* X    = (const float*)d_in[0];
    const float* Wih1 = (const float*)d_in[1];
    const float* Whh1 = (const float*)d_in[2];
    const float* bih1 = (const float*)d_in[3];
    const float* bhh1 = (const float*)d_in[4];
    const float* Wih2 = (const float*)d_in[5];
    const float* Whh2 = (const float*)d_in[6];
    const float* bih2 = (const float*)d_in[7];
    const float* bhh2 = (const float*)d_in[8];
    const float* Wlin = (const float*)d_in[9];
    const float* blin = (const float*)d_in[10];
    // d_in[11] = future = 16 (constant for this problem)

    float* ws   = (float*)d_ws;
    float* pre1 = ws + PRE1_OFF;
    float* h2a  = ws + H2A_OFF;
    float* WT   = ws + WT_OFF;
    float* Mv   = ws + MV_OFF;
    float* out  = (float*)d_out;

    hipLaunchKernelGGL(k_front,   dim3(652),     dim3(256), 0, stream,
                       X, Wih1, bih1, bhh1, Wlin, blin, pre1, WT, Mv);
    hipLaunchKernelGGL(k2_recur,  dim3(BB_),     dim3(128), 0, stream, pre1, Whh1, Wih2, Whh2,
                       bih1, bhh1, bih2, bhh2, Mv, h2a);
    hipLaunchKernelGGL(k3_outlin, dim3(TTOT_*2), dim3(256), 0, stream, h2a, WT, blin, out);
}

// Round 15
// 1006.635 us; speedup vs baseline: 1.3349x; 1.0078x over previous
//
#include <hip/hip_runtime.h>
#include <hip/hip_bf16.h>

// Problem constants (fixed by setup_inputs)
#define BB_  64
#define TT_  512
#define FF_  1024
#define HH_  31
#define GG_  124   // 4*H
#define FUT_ 16
#define TTOT_ 528  // T + future
#define OUT_ROW_ ((size_t)TTOT_ * FF_)   // per-batch stride in output

// ---- workspace layout (float indices) ----
#define PRE1_OFF ((size_t)0)                              // [512][64][128]
#define H2A_OFF  (PRE1_OFF + (size_t)TT_*64*128)          // [528*64][32]
#define WT_OFF   (H2A_OFF  + (size_t)TTOT_*64*32)         // [31][1024]
#define MV_OFF   (WT_OFF   + 31*1024)                     // [124][32]

__device__ __forceinline__ float rdlane(float v, int k) {
    return __uint_as_float(__builtin_amdgcn_readlane(__float_as_uint(v), k));
}

// repeat macros
#define REP31(M) M(0) M(1) M(2) M(3) M(4) M(5) M(6) M(7) M(8) M(9) \
                 M(10) M(11) M(12) M(13) M(14) M(15) M(16) M(17) M(18) M(19) \
                 M(20) M(21) M(22) M(23) M(24) M(25) M(26) M(27) M(28) M(29) M(30)
#define REP16E(M) M(0) M(2) M(4) M(6) M(8) M(10) M(12) M(14) \
                  M(16) M(18) M(20) M(22) M(24) M(26) M(28) M(30)
#define REP15O(M) M(1) M(3) M(5) M(7) M(9) M(11) M(13) M(15) \
                  M(17) M(19) M(21) M(23) M(25) M(27) M(29)

// ---------------- K_FRONT: fused k1(no-LDS, named-scalar acc, OPEN REG BUDGET) ----
// R14 post-mortem: named scalars removed the scratch spill (WRITE normalized)
// but VGPR_Count=24 -> the 31 loop-carried accumulators were parked in AGPRs
// (unified file; accvgpr read/write per MAC) because __launch_bounds__(256)
// with no occupancy hint makes the allocator squeeze arch VGPRs for max
// occupancy. Accumulators are NOT rematerializable, so unlike R2-R4's
// sinkable weight loads, opening the budget directly changes their placement.
// ONE CHANGE vs R14: amdgpu_waves_per_eu(2) -> 256-VGPR budget (still
// 2 blocks/CU = 2 waves/SIMD for latency hiding). Arch-VGPR accumulators
// drop the accvgpr traffic and free registers to pipeline the 31 uniform
// W loads ahead of their FMAs.
// Accumulation chain per output is k-ascending sequential adds == R0's chain
// -> pre1 BIT-IDENTICAL (absmax must stay 0.001953125; confirmed R13/R14).
// blocks 0..511: k1 (one timestep each; wave q owns gates q*31..q*31+30).
// blocks 512..635: k0 (WT transpose). blocks 636..651: k0b (Mv).
__global__ __attribute__((amdgpu_flat_work_group_size(256, 256), amdgpu_waves_per_eu(2)))
void k_front(
    const float* __restrict__ X,      // [B][T][F] fp32
    const float* __restrict__ Wih1,   // [G][F] fp32
    const float* __restrict__ bih1,
    const float* __restrict__ bhh1,
    const float* __restrict__ Wlin,   // [1024][31]
    const float* __restrict__ blin,   // [1024]
    float* __restrict__ pre1,         // [T][B][128]
    float* __restrict__ WT,           // [31][1024]
    float* __restrict__ Mv)           // [124][32]
{
    const int blk = blockIdx.x;
    const int tid = threadIdx.x;

    if (blk < 512) {
        // ---------------- k1 role: t = blk, row b = tid&63, quarter q = tid>>6 ----
        const int b  = tid & 63;
        const int t  = blk;
        const int g0 = __builtin_amdgcn_readfirstlane((tid >> 6) * 31);  // 0/31/62/93
        const float* xrow  = X + (size_t)b * TT_ * FF_ + (size_t)t * FF_;
        const float* wbase = Wih1 + (size_t)g0 * FF_;

#define ADECL(k) float a_##k = 0.0f;
        REP31(ADECL)
#undef ADECL

        float4 xv = *(const float4*)(xrow);            // prefetch chunk 0
        for (int kc = 0; kc < FF_; kc += 4) {
            const float4 xc = xv;
            const int kn = (kc + 4 < FF_) ? (kc + 4) : 0;   // guarded prefetch
            xv = *(const float4*)(xrow + kn);
#define WFMA(k) { float4 wv = *(const float4*)(wbase + (size_t)k * FF_ + kc); \
                  a_##k += xc.x * wv.x; \
                  a_##k += xc.y * wv.y; \
                  a_##k += xc.z * wv.z; \
                  a_##k += xc.w * wv.w; }
            REP31(WFMA)
#undef WFMA
        }
        // bias + store (k-ascending chain finished; same expression as R0: acc + (b1+b2))
        const int m = t * 64 + b;
        float* prow = pre1 + (size_t)m * 128 + g0;
#define STG(k) prow[k] = a_##k + (bih1[g0 + k] + bhh1[g0 + k]);
        REP31(STG)
#undef STG
        // zero pad columns 124..127 (k2's dummy lanes read them; keep finite)
        if ((tid >> 6) == 3) {
            *(float4*)(pre1 + (size_t)m * 128 + 124) = make_float4(0.f, 0.f, 0.f, 0.f);
        }
    } else if (blk < 636) {
        // ---------------- k0 role: transpose W_lin ----------------
        int i = (blk - 512) * 256 + tid;   // 124*256 = 31744 = 1024*31
        int j = i / 31;
        int k = i - j * 31;
        WT[k * 1024 + j] = Wlin[i];
    } else {
        // ---------------- k0b role: Mv ----------------
        int idx = (blk - 636) * 256 + tid;
        if (idx < GG_ * 32) {
            int g = idx >> 5, k = idx & 31;
            const float* wr = Wih1 + (size_t)g * FF_;
            float acc = 0.0f;
            if (k < 31) {
#pragma unroll 8
                for (int j = 0; j < FF_; j++) acc += wr[j] * Wlin[j * 31 + k];
            } else {
#pragma unroll 8
                for (int j = 0; j < FF_; j++) acc += wr[j] * blin[j];
            }
            Mv[idx] = acc;
        }
    }
}

// ---------------- K2: sequential recurrence (R6 version, verified 360us) ----------------
// Merged-phase (L2(t)+L1(t+1), one barrier/step), split state ownership
// (lanes 0..30 own layer-2 state, lanes 32..62 own layer-1 state), split
// accumulator chains (dep depth 62->16), 2-step pre1 prefetch.
// R7 (4-batch TLP), R11/R12 (intra-kernel overlap) all regressed: ANY
// co-residency degrades this latency-critical loop. Runs solo. Bit-identical.
__global__ __attribute__((amdgpu_flat_work_group_size(128, 128), amdgpu_waves_per_eu(1)))
void k2_recur(
    const float* __restrict__ pre1,   // [T][B][128]  (bias already folded in)
    const float* __restrict__ Whh1,   // [G][H]
    const float* __restrict__ Wih2,   // [G][H]
    const float* __restrict__ Whh2,   // [G][H]
    const float* __restrict__ bih1, const float* __restrict__ bhh1,
    const float* __restrict__ bih2, const float* __restrict__ bhh2,
    const float* __restrict__ Mv,     // [124][32]  (M | v)
    float* __restrict__ h2a)          // [528*64][32]
{
    __shared__ float gA[2][128];      // layer-1 activated gates (double-buffered)
    __shared__ float g2[2][128];      // layer-2 activated gates (double-buffered)
    const int L  = threadIdx.x;       // 0..127
    const int bb = blockIdx.x;
    const int j  = L & 63;            // in-wave lane
    const int gc = (L < GG_) ? L : (GG_ - 1);   // clamped gate id for safe loads
    const bool isg = (gc >= 62 && gc < 93);     // tanh gate?
    const bool selhi = (j >= 32);               // h1-owner half of the wave
    const int sidx = selhi ? (j - 32) : j;      // state index this lane owns

    // recurrent weights as NAMED scalars: row gc of each [124][31] matrix
#define WLOAD(k) float w1_##k  = Whh1[gc * 31 + k]; \
                 float wi2_##k = Wih2[gc * 31 + k]; \
                 float wh2_##k = Whh2[gc * 31 + k];
    REP31(WLOAD)
#undef WLOAD
#define WPIN(k) asm("" : "+v"(w1_##k), "+v"(wi2_##k), "+v"(wh2_##k));
    REP31(WPIN)
#undef WPIN

    const float b2c = bih2[gc] + bhh2[gc];

    // unified state: lanes 0..30 hold (cv2,hv2)[j]; lanes 32..62 hold (cv1,hv1)[j-32]
    float hv = 0.0f, cv = 0.0f;

    // ---- prologue: layer-1 gates for t=0 (h1(-1)=0 -> dot contributes zeros) ----
    float cur0 = pre1[(size_t)bb * 128 + L];
    float pnxt = pre1[((size_t)1 * 64 + bb) * 128 + L];   // p(1)
    float pnx2 = pre1[((size_t)2 * 64 + bb) * 128 + L];   // p(2)
    {
        float pa0 = cur0, pa1 = 0.0f;
#define DPE(k) { float hk = rdlane(hv, 32 + k); pa0 += w1_##k * hk; }
#define DPO(k) { float hk = rdlane(hv, 32 + k); pa1 += w1_##k * hk; }
        REP16E(DPE)
        REP15O(DPO)
#undef DPE
#undef DPO
        float a = pa0 + pa1;
        float z = isg ? (2.0f * a) : a;
        float s = 1.0f / (1.0f + __expf(-z));
        gA[1][L] = isg ? (2.0f * s - 1.0f) : s;
    }
    __syncthreads();
    {
        // h1-owners (lanes 32..62) take h1(0); h2-owners stay at 0
        const float* gsrc = &gA[1][0];
        float ig = gsrc[sidx];
        float fg = gsrc[sidx + 31];
        float gg = gsrc[sidx + 62];
        float og = gsrc[sidx + 93];
        float cvn = fg * cv + ig * gg;
        float e = __expf(-2.0f * cvn);
        float hvn = og * (2.0f / (1.0f + e) - 1.0f);
        cv = selhi ? cvn : 0.0f;
        hv = selhi ? hvn : 0.0f;
    }

    // ---- main merged loop: iteration t computes L2(t) + L1(t+1), t = 0..510 ----
    for (int t = 0; t < TT_ - 1; t++) {
        const int pb = t & 1;
        const float cur = pnxt;
        pnxt = pnx2;
        if (t + 3 < TT_) pnx2 = pre1[((size_t)(t + 3) * 64 + bb) * 128 + L];

        // split-chain dots: h1k = rdlane(hv,32+k), h2k = rdlane(hv,k)
        float bi0 = b2c, bi1 = 0.0f, bh0 = 0.0f, bh1 = 0.0f;
        float pa0 = cur, pa1 = 0.0f;
#define DME(k) { float h1k = rdlane(hv, 32 + k); float h2k = rdlane(hv, k); \
                 bi0 += wi2_##k * h1k; bh0 += wh2_##k * h2k; pa0 += w1_##k * h1k; }
#define DMO(k) { float h1k = rdlane(hv, 32 + k); float h2k = rdlane(hv, k); \
                 bi1 += wi2_##k * h1k; bh1 += wh2_##k * h2k; pa1 += w1_##k * h1k; }
        REP16E(DME)
        REP15O(DMO)
#undef DME
#undef DMO
        float b = (bi0 + bi1) + (bh0 + bh1);
        float a = pa0 + pa1;
        {
            float z = isg ? (2.0f * b) : b;
            float s = 1.0f / (1.0f + __expf(-z));
            g2[pb][L] = isg ? (2.0f * s - 1.0f) : s;
        }
        {
            float z = isg ? (2.0f * a) : a;
            float s = 1.0f / (1.0f + __expf(-z));
            gA[pb][L] = isg ? (2.0f * s - 1.0f) : s;
        }
        __syncthreads();
        {
            // unified branchless state update: h2-owners read g2 (L2 gates of t),
            // h1-owners read gA (L1 gates of t+1).
            const float* gsrc = selhi ? &gA[pb][0] : &g2[pb][0];
            float ig = gsrc[sidx];
            float fg = gsrc[sidx + 31];
            float gg = gsrc[sidx + 62];
            float og = gsrc[sidx + 93];
            cv = fg * cv + ig * gg;
            float e = __expf(-2.0f * cv);
            hv = og * (2.0f / (1.0f + e) - 1.0f);
        }
        if (L < HH_) h2a[((size_t)t * 64 + bb) * 32 + L] = hv;   // h2(t)
    }

    // ---- tail: L2(511) only ----
    {
        float bi0 = b2c, bi1 = 0.0f, bh0 = 0.0f, bh1 = 0.0f;
#define DTE(k) { float h1k = rdlane(hv, 32 + k); float h2k = rdlane(hv, k); \
                 bi0 += wi2_##k * h1k; bh0 += wh2_##k * h2k; }
#define DTO(k) { float h1k = rdlane(hv, 32 + k); float h2k = rdlane(hv, k); \
                 bi1 += wi2_##k * h1k; bh1 += wh2_##k * h2k; }
        REP16E(DTE)
        REP15O(DTO)
#undef DTE
#undef DTO
        float b = (bi0 + bi1) + (bh0 + bh1);
        float z = isg ? (2.0f * b) : b;
        float s = 1.0f / (1.0f + __expf(-z));
        g2[1][L] = isg ? (2.0f * s - 1.0f) : s;
    }
    __syncthreads();
    {
        const float* gsrc = &g2[1][0];
        float ig = gsrc[sidx];
        float fg = gsrc[sidx + 31];
        float gg = gsrc[sidx + 62];
        float og = gsrc[sidx + 93];
        float cvn = fg * cv + ig * gg;
        float e = __expf(-2.0f * cvn);
        float hvn = og * (2.0f / (1.0f + e) - 1.0f);
        cv = selhi ? cv : cvn;          // only h2-owners update
        hv = selhi ? hv : hvn;
    }
    if (L < HH_) h2a[((size_t)(TT_ - 1) * 64 + bb) * 32 + L] = hv;   // h2(511)

    // ---- autoregressive future: pregate = M*h2 + v + b1 (1024-dot eliminated) ----
#define MLOAD(k) float m_##k = Mv[gc * 32 + k];
    REP31(MLOAD)
#undef MLOAD
    float m_31 = Mv[gc * 32 + 31];
#define MPIN(k) asm("" : "+v"(m_##k));
    REP31(MPIN)
#undef MPIN
    asm("" : "+v"(m_31));
    const float b1c = bih1[gc] + bhh1[gc];

    for (int sft = 0; sft < FUT_; sft++) {
        float pa0 = b1c + m_31, pa1 = 0.0f;
#define DFE(k) { float h2k = rdlane(hv, k); pa0 += m_##k * h2k; }
#define DFO(k) { float h2k = rdlane(hv, k); pa1 += m_##k * h2k; }
        REP16E(DFE)
        REP15O(DFO)
#undef DFE
#undef DFO
#define DGE(k) { float h1k = rdlane(hv, 32 + k); pa0 += w1_##k * h1k; }
#define DGO(k) { float h1k = rdlane(hv, 32 + k); pa1 += w1_##k * h1k; }
        REP16E(DGE)
        REP15O(DGO)
#undef DGE
#undef DGO
        {
            float a = pa0 + pa1;
            float z = isg ? (2.0f * a) : a;
            float s = 1.0f / (1.0f + __expf(-z));
            gA[0][L] = isg ? (2.0f * s - 1.0f) : s;
        }
        __syncthreads();
        {
            const float* gsrc = &gA[0][0];
            float ig = gsrc[sidx];
            float fg = gsrc[sidx + 31];
            float gg = gsrc[sidx + 62];
            float og = gsrc[sidx + 93];
            float cvn = fg * cv + ig * gg;
            float e = __expf(-2.0f * cvn);
            float hvn = og * (2.0f / (1.0f + e) - 1.0f);
            cv = selhi ? cvn : cv;      // only h1-owners update
            hv = selhi ? hvn : hv;
        }
        float bi0 = b2c, bi1 = 0.0f, bh0 = 0.0f, bh1 = 0.0f;
#define DHE(k) { float h1k = rdlane(hv, 32 + k); float h2k = rdlane(hv, k); \
                 bi0 += wi2_##k * h1k; bh0 += wh2_##k * h2k; }
#define DHO(k) { float h1k = rdlane(hv, 32 + k); float h2k = rdlane(hv, k); \
                 bi1 += wi2_##k * h1k; bh1 += wh2_##k * h2k; }
        REP16E(DHE)
        REP15O(DHO)
#undef DHE
#undef DHO
        {
            float b = (bi0 + bi1) + (bh0 + bh1);
            float z = isg ? (2.0f * b) : b;
            float s = 1.0f / (1.0f + __expf(-z));
            g2[0][L] = isg ? (2.0f * s - 1.0f) : s;
        }
        __syncthreads();
        {
            const float* gsrc = &g2[0][0];
            float ig = gsrc[sidx];
            float fg = gsrc[sidx + 31];
            float gg = gsrc[sidx + 62];
            float og = gsrc[sidx + 93];
            float cvn = fg * cv + ig * gg;
            float e = __expf(-2.0f * cvn);
            float hvn = og * (2.0f / (1.0f + e) - 1.0f);
            cv = selhi ? cv : cvn;      // only h2-owners update
            hv = selhi ? hv : hvn;
        }
        if (L < HH_) h2a[((size_t)(TT_ + sft) * 64 + bb) * 32 + L] = hv;
    }
}

// ---------------- K3 v2: output linear, 32 rows/block (R9 verified) ----------------
__global__ __launch_bounds__(256) void k3_outlin(
    const float* __restrict__ h2a,   // [528*64][32]
    const float* __restrict__ WT,    // [31][1024]
    const float* __restrict__ blin,  // [1024]
    float* __restrict__ out)         // [B][528][1024] fp32
{
    __shared__ __align__(16) float hl[32][32];
    const int tid = threadIdx.x;
    const int m0  = blockIdx.x * 32;
#pragma unroll
    for (int p = 0; p < 4; p++) {
        int i = tid + p * 256;
        int r = i >> 5, k = i & 31;
        hl[r][k] = h2a[(size_t)(m0 + r) * 32 + k];
    }
    __syncthreads();
    const int c0 = tid * 4;
    float4 bl = *(const float4*)(blin + c0);
    float4 acc[32];
#pragma unroll
    for (int r = 0; r < 32; r++) acc[r] = bl;
    for (int k = 0; k < 31; k++) {
        float4 wv = *(const float4*)(WT + k * 1024 + c0);
#pragma unroll
        for (int r = 0; r < 32; r++) {
            float h = hl[r][k];
            acc[r].x += h * wv.x; acc[r].y += h * wv.y;
            acc[r].z += h * wv.z; acc[r].w += h * wv.w;
        }
    }
    const int t  = m0 >> 6;
    const int b0 = m0 & 63;
#pragma unroll
    for (int r = 0; r < 32; r++) {
        int b = b0 + r;
        *(float4*)(out + (size_t)b * OUT_ROW_ + (size_t)t * FF_ + c0) = acc[r];
    }
}

extern "C" void kernel_launch(void* const* d_in, const int* in_sizes, int n_in,
                              void* d_out, int out_size, void* d_ws, size_t ws_size,
                              hipStream_t stream) {
    (void)in_sizes; (void)n_in; (void)out_size; (void)ws_size;
    const float* X    = (const float*)d_in[0];
    const float* Wih1 = (const float*)d_in[1];
    const float* Whh1 = (const float*)d_in[2];
    const float* bih1 = (const float*)d_in[3];
    const float* bhh1 = (const float*)d_in[4];
    const float* Wih2 = (const float*)d_in[5];
    const float* Whh2 = (const float*)d_in[6];
    const float* bih2 = (const float*)d_in[7];
    const float* bhh2 = (const float*)d_in[8];
    const float* Wlin = (const float*)d_in[9];
    const float* blin = (const float*)d_in[10];
    // d_in[11] = future = 16 (constant for this problem)

    float* ws   = (float*)d_ws;
    float* pre1 = ws + PRE1_OFF;
    float* h2a  = ws + H2A_OFF;
    float* WT   = ws + WT_OFF;
    float* Mv   = ws + MV_OFF;
    float* out  = (float*)d_out;

    hipLaunchKernelGGL(k_front,   dim3(652),     dim3(256), 0, stream,
                       X, Wih1, bih1, bhh1, Wlin, blin, pre1, WT, Mv);
    hipLaunchKernelGGL(k2_recur,  dim3(BB_),     dim3(128), 0, stream, pre1, Whh1, Wih2, Whh2,
                       bih1, bhh1, bih2, bhh2, Mv, h2a);
    hipLaunchKernelGGL(k3_outlin, dim3(TTOT_*2), dim3(256), 0, stream, h2a, WT, blin, out);
}